// Round 3
// baseline (104.815 us; speedup 1.0000x reference)
//
#include <hip/hip_runtime.h>
#include <math.h>

#define NBINS 15
#define THREADS 256
#define GRID 1536  // 6 blocks/CU * 256 CUs, matches __launch_bounds__(256,6) residency

struct Accum {
  double d[NBINS];  // sum over bin of (conf - correct); ECE = sum |d[b]| / n
};

__device__ __forceinline__ void process_row(float l0, float l1, float l2, int lab,
                                            float* h) {
  float m = fmaxf(l0, fmaxf(l1, l2));  // v_max3
  float s = __expf(l0 - m) + __expf(l1 - m) + __expf(l2 - m);
  float conf = __fdividef(1.0f, s);  // max prob = 1/s
  int pred = 0;
  float best = l0;
  if (l1 > best) { pred = 1; best = l1; }
  if (l2 > best) { pred = 2; }
  float val = conf - ((pred == lab) ? 1.0f : 0.0f);
  // bin i covers (i/15,(i+1)/15]; searchsorted(uppers, conf, 'left') == ceil(conf*15)-1
  int bin = (int)ceilf(conf * 15.0f) - 1;
  bin = bin < 0 ? 0 : (bin > NBINS - 1 ? NBINS - 1 : bin);
  atomicAdd(&h[bin], val);  // ds_add_f32: fire-and-forget, no dependency chain
}

__global__ __launch_bounds__(THREADS, 6) void ece_main(
    const float4* __restrict__ logits4, const int4* __restrict__ labels4,
    Accum* __restrict__ ws, int n) {
  __shared__ float hist[THREADS / 64][16];  // per-wave slice, 16-float stride
  if (threadIdx.x < (THREADS / 64) * 16) ((float*)hist)[threadIdx.x] = 0.0f;
  __syncthreads();
  float* h = hist[threadIdx.x >> 6];

  const int npairs = n >> 3;  // 8 rows (2 quads) per iteration
  const int total = gridDim.x * blockDim.x;
  for (int p = blockIdx.x * blockDim.x + threadIdx.x; p < npairs; p += total) {
    const float4* lp = logits4 + 6 * (size_t)p;
    float4 x0 = lp[0], y0 = lp[1], z0 = lp[2];
    float4 x1 = lp[3], y1 = lp[4], z1 = lp[5];
    int4 la = labels4[2 * p + 0];
    int4 lc = labels4[2 * p + 1];
    process_row(x0.x, x0.y, x0.z, la.x, h);
    process_row(x0.w, y0.x, y0.y, la.y, h);
    process_row(y0.z, y0.w, z0.x, la.z, h);
    process_row(z0.y, z0.z, z0.w, la.w, h);
    process_row(x1.x, x1.y, x1.z, lc.x, h);
    process_row(x1.w, y1.x, y1.y, lc.y, h);
    process_row(y1.z, y1.w, z1.x, lc.z, h);
    process_row(z1.y, z1.z, z1.w, lc.w, h);
  }
  // tail rows if n % 8 != 0 (not hit for N=2^24)
  if (blockIdx.x == 0 && threadIdx.x == 0) {
    const float* lf = (const float*)logits4;
    const int* li = (const int*)labels4;
    for (int r = (n >> 3) << 3; r < n; ++r)
      process_row(lf[3 * r], lf[3 * r + 1], lf[3 * r + 2], li[r], h);
  }

  __syncthreads();
  if (threadIdx.x < NBINS) {
    float v = 0.0f;
#pragma unroll
    for (int w = 0; w < THREADS / 64; ++w) v += hist[w][threadIdx.x];
    atomicAdd(&ws->d[threadIdx.x], (double)v);
  }
}

__global__ void ece_final(const Accum* __restrict__ ws, float* __restrict__ out, int n) {
  if (threadIdx.x == 0 && blockIdx.x == 0) {
    double ece = 0.0;
    for (int b = 0; b < NBINS; ++b) ece += fabs(ws->d[b]);
    out[0] = (float)(ece / (double)n);
  }
}

extern "C" void kernel_launch(void* const* d_in, const int* in_sizes, int n_in,
                              void* d_out, int out_size, void* d_ws, size_t ws_size,
                              hipStream_t stream) {
  const float4* logits4 = (const float4*)d_in[0];
  const int4* labels4 = (const int4*)d_in[1];
  const int n = in_sizes[1];  // rows == number of labels
  Accum* ws = (Accum*)d_ws;
  hipMemsetAsync(d_ws, 0, sizeof(Accum), stream);
  ece_main<<<GRID, THREADS, 0, stream>>>(logits4, labels4, ws, n);
  ece_final<<<1, 64, 0, stream>>>(ws, (float*)d_out, n);
}

// Round 4
// 58.939 us; speedup vs baseline: 1.7784x; 1.7784x over previous
//
#include <hip/hip_runtime.h>
#include <math.h>

#define NBINS 15
#define THREADS 256
#define GRID 2048          // 8 blocks/CU * 256 CUs; exactly 8 iters/thread at N=2^24
#define BIN_LO 4           // C=3 => conf >= 1/3 => bins 4..14 only
#define NACC (NBINS - BIN_LO)  // 11 register accumulators

__device__ __forceinline__ void process_row(float l0, float l1, float l2, int lab,
                                            float* a) {
  float m = fmaxf(l0, fmaxf(l1, l2));        // v_max3_f32
  float s = __expf(l0 - m) + __expf(l1 - m) + __expf(l2 - m);
  float conf = __builtin_amdgcn_rcpf(s);     // max prob = 1/s
  // correct <=> logit[label] equals the max (ties measure-zero, under threshold)
  float lm = (lab == 1) ? l1 : ((lab == 2) ? l2 : l0);
  float val = conf - ((lm >= m) ? 1.0f : 0.0f);
  // bin i covers (i/15,(i+1)/15]; searchsorted(uppers,conf,'left') == ceil(conf*15)-1
  int bin = (int)ceilf(conf * 15.0f) - 1;
  bin = bin < BIN_LO ? BIN_LO : (bin > NBINS - 1 ? NBINS - 1 : bin);
#pragma unroll
  for (int b = BIN_LO; b < NBINS; ++b) a[b - BIN_LO] += (bin == b) ? val : 0.0f;
}

__global__ __launch_bounds__(THREADS, 8) void ece_main(
    const float4* __restrict__ logits4, const int4* __restrict__ labels4,
    float* __restrict__ partial, int n) {
  float a[NACC];
#pragma unroll
  for (int i = 0; i < NACC; ++i) a[i] = 0.0f;

  const int nquads = n >> 2;
  const int total = gridDim.x * blockDim.x;
  int q = blockIdx.x * blockDim.x + threadIdx.x;
  if (q < nquads) {
    // manual double-buffer: loads for iter k+1 issued before processing iter k
    float4 x = logits4[3 * (size_t)q + 0];
    float4 y = logits4[3 * (size_t)q + 1];
    float4 z = logits4[3 * (size_t)q + 2];
    int4 lb = labels4[q];
    for (;;) {
      const int qn = q + total;
      const bool more = qn < nquads;
      float4 xn, yn, zn;
      int4 lbn;
      if (more) {
        xn = logits4[3 * (size_t)qn + 0];
        yn = logits4[3 * (size_t)qn + 1];
        zn = logits4[3 * (size_t)qn + 2];
        lbn = labels4[qn];
      }
      process_row(x.x, x.y, x.z, lb.x, a);
      process_row(x.w, y.x, y.y, lb.y, a);
      process_row(y.z, y.w, z.x, lb.z, a);
      process_row(z.y, z.z, z.w, lb.w, a);
      if (!more) break;
      x = xn; y = yn; z = zn; lb = lbn; q = qn;
    }
  }

  // wave butterfly reduce, then cross-wave via tiny LDS
#pragma unroll
  for (int i = 0; i < NACC; ++i) {
    float v = a[i];
#pragma unroll
    for (int off = 32; off > 0; off >>= 1) v += __shfl_down(v, off, 64);
    a[i] = v;
  }
  __shared__ float s_part[THREADS / 64][NACC];
  const int wave = threadIdx.x >> 6;
  const int lane = threadIdx.x & 63;
  if (lane == 0) {
#pragma unroll
    for (int i = 0; i < NACC; ++i) s_part[wave][i] = a[i];
  }
  __syncthreads();
  if (threadIdx.x < NACC) {
    float v = 0.0f;
#pragma unroll
    for (int w = 0; w < THREADS / 64; ++w) v += s_part[w][threadIdx.x];
    // [bin][block] layout: no atomics, no zero-init of ws needed
    partial[(size_t)threadIdx.x * gridDim.x + blockIdx.x] = v;
  }
}

__global__ __launch_bounds__(1024) void ece_final(
    const float* __restrict__ partial, const float* __restrict__ logits,
    const int* __restrict__ labels, float* __restrict__ out, int n, int nblocks) {
  __shared__ double sbin[NACC];
  const int wave = threadIdx.x >> 6;
  const int lane = threadIdx.x & 63;
  if (wave < NACC) {
    double v = 0.0;
    for (int i = lane; i < nblocks; i += 64)
      v += (double)partial[(size_t)wave * nblocks + i];
#pragma unroll
    for (int off = 32; off > 0; off >>= 1) v += __shfl_down(v, off, 64);
    if (lane == 0) sbin[wave] = v;
  }
  __syncthreads();
  if (threadIdx.x == 0) {
    float t[NACC];
#pragma unroll
    for (int i = 0; i < NACC; ++i) t[i] = 0.0f;
    for (int r = (n >> 2) << 2; r < n; ++r)  // tail rows (none for N=2^24)
      process_row(logits[3 * r], logits[3 * r + 1], logits[3 * r + 2], labels[r], t);
    double ece = 0.0;
    for (int b = 0; b < NACC; ++b) ece += fabs(sbin[b] + (double)t[b]);
    out[0] = (float)(ece / (double)n);
  }
}

extern "C" void kernel_launch(void* const* d_in, const int* in_sizes, int n_in,
                              void* d_out, int out_size, void* d_ws, size_t ws_size,
                              hipStream_t stream) {
  const float4* logits4 = (const float4*)d_in[0];
  const int4* labels4 = (const int4*)d_in[1];
  const int n = in_sizes[1];  // rows == number of labels
  float* partial = (float*)d_ws;  // [NACC][GRID] floats
  ece_main<<<GRID, THREADS, 0, stream>>>(logits4, labels4, partial, n);
  ece_final<<<1, 1024, 0, stream>>>(partial, (const float*)d_in[0],
                                    (const int*)d_in[1], (float*)d_out, n, GRID);
}